// Round 1
// baseline (207.283 us; speedup 1.0000x reference)
//
#include <hip/hip_runtime.h>
#include <stdint.h>

#define B_   16384
#define D_   512
#define N1_  1024   // 2D
#define K1_  512    // D
#define N2_  512
#define K2_  1024

typedef _Float16 f16x8 __attribute__((ext_vector_type(8)));
typedef float    f32x4 __attribute__((ext_vector_type(4)));

__device__ __forceinline__ void gl_lds16(const void* g, void* l) {
  __builtin_amdgcn_global_load_lds(
      (const __attribute__((address_space(1))) uint32_t*)g,
      (__attribute__((address_space(3))) uint32_t*)l, 16, 0, 0);
}

// ---------------- prep kernels ----------------

// z (fp32) -> zh,zl fp16 split, scaled x16
__global__ __launch_bounds__(256) void convert_z(const float* __restrict__ z,
                                                 _Float16* __restrict__ zh,
                                                 _Float16* __restrict__ zl) {
  int i = blockIdx.x * 256 + threadIdx.x;          // quad index, 2097152 total
  float4 v = ((const float4*)z)[i];
  union { _Float16 h[4]; ushort4 u; } H, L;
  float x;
  x = v.x * 16.f; H.h[0] = (_Float16)x; L.h[0] = (_Float16)(x - (float)H.h[0]);
  x = v.y * 16.f; H.h[1] = (_Float16)x; L.h[1] = (_Float16)(x - (float)H.h[1]);
  x = v.z * 16.f; H.h[2] = (_Float16)x; L.h[2] = (_Float16)(x - (float)H.h[2]);
  x = v.w * 16.f; H.h[3] = (_Float16)x; L.h[3] = (_Float16)(x - (float)H.h[3]);
  ((ushort4*)zh)[i] = H.u;
  ((ushort4*)zl)[i] = L.u;
}

// W1 (1024 x 513 fp32) -> w1h,w1l (1024 x 512 fp16), scaled x64
__global__ __launch_bounds__(256) void convert_w1(const float* __restrict__ W1,
                                                  _Float16* __restrict__ w1h,
                                                  _Float16* __restrict__ w1l) {
  int idx = blockIdx.x * 256 + threadIdx.x;        // 524288 total
  int j = idx >> 9, k = idx & 511;
  float x = W1[(size_t)j * 513 + k] * 64.f;
  _Float16 hh = (_Float16)x;
  w1h[idx] = hh;
  w1l[idx] = (_Float16)(x - (float)hh);
}

// W2 (512 x 1025 fp32) -> w2h (512 x 1024 fp16), unscaled
__global__ __launch_bounds__(256) void convert_w2(const float* __restrict__ W2,
                                                  _Float16* __restrict__ w2h) {
  int idx = blockIdx.x * 256 + threadIdx.x;        // 524288 total
  int i = idx >> 10, j = idx & 1023;
  w2h[idx] = (_Float16)W2[(size_t)i * 1025 + j];
}

// bias1[j] = b1[j] + t*W1[j,512] ; bias2[i] = b2[i] + t*W2[i,1024]
__global__ __launch_bounds__(256) void prep_bias(const float* __restrict__ t,
                                                 const float* __restrict__ W1,
                                                 const float* __restrict__ b1,
                                                 const float* __restrict__ W2,
                                                 const float* __restrict__ b2,
                                                 float* __restrict__ bias1,
                                                 float* __restrict__ bias2) {
  int j = blockIdx.x * 256 + threadIdx.x;          // 1024 total
  float t0 = t[0];
  if (j < 1024) bias1[j] = b1[j] + t0 * W1[(size_t)j * 513 + 512];
  if (j < 512)  bias2[j] = b2[j] + t0 * W2[(size_t)j * 1025 + 1024];
}

// c[j] = sum_k W2[k,j] * W1[j,k], one wave per j
__global__ __launch_bounds__(256) void compute_c(const float* __restrict__ W1,
                                                 const float* __restrict__ W2,
                                                 float* __restrict__ cvec) {
  int wave = threadIdx.x >> 6, lane = threadIdx.x & 63;
  int j = blockIdx.x * 4 + wave;                   // 256 blocks -> j in [0,1024)
  float s = 0.f;
  #pragma unroll
  for (int kk = 0; kk < 8; ++kk) {
    int k = lane + kk * 64;
    s += W2[(size_t)k * 1025 + j] * W1[(size_t)j * 513 + k];
  }
  #pragma unroll
  for (int off = 32; off > 0; off >>= 1) s += __shfl_xor(s, off);
  if (lane == 0) cvec[j] = s;
}

// ---------------- GEMM1: h_pre = z@W1z^T (split fp16, 3 MFMA), h + trace ----------------

__global__ __launch_bounds__(256, 2)
void gemm1_kernel(const _Float16* __restrict__ zh, const _Float16* __restrict__ zl,
                  const _Float16* __restrict__ w1h, const _Float16* __restrict__ w1l,
                  const float* __restrict__ bias1, const float* __restrict__ cvec,
                  _Float16* __restrict__ hOut, float* __restrict__ dlogp) {
  __shared__ _Float16 Ah[128 * 32], Al[128 * 32], Bh[128 * 32], Bl[128 * 32];
  const int tid = threadIdx.x;
  const int lane = tid & 63, wave = tid >> 6;
  const int wm = wave >> 1, wn = wave & 1;
  const int q = lane >> 4, m16 = lane & 15;
  const int bm = blockIdx.y, bn = blockIdx.x;

  // staging coords: chunk c covers row=c>>2, k-col=(c&3)*8 (16B)
  const int c0 = tid, c1 = 256 + tid;
  const int r0 = c0 >> 2, kc0 = (c0 & 3) << 3;
  const int r1 = c1 >> 2, kc1 = (c1 & 3) << 3;
  const _Float16* zh0 = zh + (size_t)(bm * 128 + r0) * K1_ + kc0;
  const _Float16* zh1 = zh + (size_t)(bm * 128 + r1) * K1_ + kc1;
  const _Float16* zl0 = zl + (size_t)(bm * 128 + r0) * K1_ + kc0;
  const _Float16* zl1 = zl + (size_t)(bm * 128 + r1) * K1_ + kc1;
  const _Float16* wh0 = w1h + (size_t)(bn * 128 + r0) * K1_ + kc0;
  const _Float16* wh1 = w1h + (size_t)(bn * 128 + r1) * K1_ + kc1;
  const _Float16* wl0 = w1l + (size_t)(bn * 128 + r0) * K1_ + kc0;
  const _Float16* wl1 = w1l + (size_t)(bn * 128 + r1) * K1_ + kc1;

  f32x4 acc[4][4] = {};

  for (int k0 = 0; k0 < K1_; k0 += 32) {
    gl_lds16(zh0 + k0, &Ah[c0 * 8]);
    gl_lds16(zh1 + k0, &Ah[c1 * 8]);
    gl_lds16(zl0 + k0, &Al[c0 * 8]);
    gl_lds16(zl1 + k0, &Al[c1 * 8]);
    gl_lds16(wh0 + k0, &Bh[c0 * 8]);
    gl_lds16(wh1 + k0, &Bh[c1 * 8]);
    gl_lds16(wl0 + k0, &Bl[c0 * 8]);
    gl_lds16(wl1 + k0, &Bl[c1 * 8]);
    __syncthreads();
    f16x8 ah[4], al[4], bh[4], bl[4];
    #pragma unroll
    for (int mt = 0; mt < 4; ++mt) {
      int r = wm * 64 + mt * 16 + m16;
      ah[mt] = *(const f16x8*)&Ah[r * 32 + q * 8];
      al[mt] = *(const f16x8*)&Al[r * 32 + q * 8];
    }
    #pragma unroll
    for (int nt = 0; nt < 4; ++nt) {
      int r = wn * 64 + nt * 16 + m16;
      bh[nt] = *(const f16x8*)&Bh[r * 32 + q * 8];
      bl[nt] = *(const f16x8*)&Bl[r * 32 + q * 8];
    }
    #pragma unroll
    for (int mt = 0; mt < 4; ++mt)
      #pragma unroll
      for (int nt = 0; nt < 4; ++nt) {
        acc[mt][nt] = __builtin_amdgcn_mfma_f32_16x16x32_f16(ah[mt], bh[nt], acc[mt][nt], 0, 0, 0);
        acc[mt][nt] = __builtin_amdgcn_mfma_f32_16x16x32_f16(ah[mt], bl[nt], acc[mt][nt], 0, 0, 0);
        acc[mt][nt] = __builtin_amdgcn_mfma_f32_16x16x32_f16(al[mt], bh[nt], acc[mt][nt], 0, 0, 0);
      }
    __syncthreads();
  }

  // epilogue: h = relu(acc/1024 + bias1), trace += mask*c
  float tr[16];
  #pragma unroll
  for (int i = 0; i < 16; ++i) tr[i] = 0.f;
  #pragma unroll
  for (int nt = 0; nt < 4; ++nt) {
    int col = bn * 128 + wn * 64 + nt * 16 + m16;
    float cj = cvec[col];
    float bj = bias1[col];
    #pragma unroll
    for (int mt = 0; mt < 4; ++mt) {
      int rowb = bm * 128 + wm * 64 + mt * 16 + q * 4;
      #pragma unroll
      for (int r = 0; r < 4; ++r) {
        float hp = acc[mt][nt][r] * (1.f / 1024.f) + bj;
        float h = hp > 0.f ? hp : 0.f;
        hOut[(size_t)(rowb + r) * N1_ + col] = (_Float16)h;
        if (hp > 0.f) tr[mt * 4 + r] += cj;
      }
    }
  }
  #pragma unroll
  for (int off = 1; off < 16; off <<= 1)
    #pragma unroll
    for (int i = 0; i < 16; ++i) tr[i] += __shfl_xor(tr[i], off);
  if (m16 == 0) {
    #pragma unroll
    for (int mt = 0; mt < 4; ++mt)
      #pragma unroll
      for (int r = 0; r < 4; ++r)
        atomicAdd(&dlogp[bm * 128 + wm * 64 + mt * 16 + q * 4 + r], -tr[mt * 4 + r]);
  }
}

// ---------------- GEMM2: dz = h@W2h^T + bias2 ----------------

__global__ __launch_bounds__(256, 2)
void gemm2_kernel(const _Float16* __restrict__ h, const _Float16* __restrict__ w2,
                  const float* __restrict__ bias2, float* __restrict__ out) {
  __shared__ _Float16 As[128 * 32], Bs[128 * 32];
  const int tid = threadIdx.x;
  const int lane = tid & 63, wave = tid >> 6;
  const int wm = wave >> 1, wn = wave & 1;
  const int q = lane >> 4, m16 = lane & 15;
  const int bm = blockIdx.y, bn = blockIdx.x;

  const int c0 = tid, c1 = 256 + tid;
  const int r0 = c0 >> 2, kc0 = (c0 & 3) << 3;
  const int r1 = c1 >> 2, kc1 = (c1 & 3) << 3;
  const _Float16* hA0 = h + (size_t)(bm * 128 + r0) * K2_ + kc0;
  const _Float16* hA1 = h + (size_t)(bm * 128 + r1) * K2_ + kc1;
  const _Float16* wB0 = w2 + (size_t)(bn * 128 + r0) * K2_ + kc0;
  const _Float16* wB1 = w2 + (size_t)(bn * 128 + r1) * K2_ + kc1;

  f32x4 acc[4][4] = {};

  for (int k0 = 0; k0 < K2_; k0 += 32) {
    gl_lds16(hA0 + k0, &As[c0 * 8]);
    gl_lds16(hA1 + k0, &As[c1 * 8]);
    gl_lds16(wB0 + k0, &Bs[c0 * 8]);
    gl_lds16(wB1 + k0, &Bs[c1 * 8]);
    __syncthreads();
    f16x8 af[4], bf[4];
    #pragma unroll
    for (int mt = 0; mt < 4; ++mt) {
      int r = wm * 64 + mt * 16 + m16;
      af[mt] = *(const f16x8*)&As[r * 32 + q * 8];
    }
    #pragma unroll
    for (int nt = 0; nt < 4; ++nt) {
      int r = wn * 64 + nt * 16 + m16;
      bf[nt] = *(const f16x8*)&Bs[r * 32 + q * 8];
    }
    #pragma unroll
    for (int mt = 0; mt < 4; ++mt)
      #pragma unroll
      for (int nt = 0; nt < 4; ++nt)
        acc[mt][nt] = __builtin_amdgcn_mfma_f32_16x16x32_f16(af[mt], bf[nt], acc[mt][nt], 0, 0, 0);
    __syncthreads();
  }

  #pragma unroll
  for (int nt = 0; nt < 4; ++nt) {
    int col = bn * 128 + wn * 64 + nt * 16 + m16;
    float bj = bias2[col];
    #pragma unroll
    for (int mt = 0; mt < 4; ++mt) {
      int rowb = bm * 128 + wm * 64 + mt * 16 + q * 4;
      #pragma unroll
      for (int r = 0; r < 4; ++r)
        out[(size_t)(rowb + r) * N2_ + col] = acc[mt][nt][r] + bj;
    }
  }
}

// ---------------- launcher ----------------

extern "C" void kernel_launch(void* const* d_in, const int* in_sizes, int n_in,
                              void* d_out, int out_size, void* d_ws, size_t ws_size,
                              hipStream_t stream) {
  const float* t  = (const float*)d_in[0];
  const float* z  = (const float*)d_in[1];
  // d_in[2] = logp_z, unused
  const float* W1 = (const float*)d_in[3];
  const float* b1 = (const float*)d_in[4];
  const float* W2 = (const float*)d_in[5];
  const float* b2 = (const float*)d_in[6];

  float* out   = (float*)d_out;
  float* dlogp = out + (size_t)B_ * D_;

  char* ws = (char*)d_ws;
  _Float16* zh   = (_Float16*)ws; ws += (size_t)B_ * K1_ * 2;   // 16 MB
  _Float16* zl   = (_Float16*)ws; ws += (size_t)B_ * K1_ * 2;   // 16 MB
  _Float16* w1h  = (_Float16*)ws; ws += (size_t)N1_ * K1_ * 2;  // 1 MB
  _Float16* w1l  = (_Float16*)ws; ws += (size_t)N1_ * K1_ * 2;  // 1 MB
  _Float16* w2h  = (_Float16*)ws; ws += (size_t)N2_ * K2_ * 2;  // 1 MB
  float*    bias1 = (float*)ws;   ws += 1024 * 4;
  float*    bias2 = (float*)ws;   ws += 512 * 4;   // keep 256B multiples overall
  float*    cvec  = (float*)ws;   ws += 1024 * 4;
  _Float16* hWs  = (_Float16*)ws; ws += (size_t)B_ * N1_ * 2;   // 32 MB

  hipMemsetAsync(dlogp, 0, B_ * sizeof(float), stream);
  convert_z <<<(B_ * K1_ / 4) / 256, 256, 0, stream>>>(z, zh, zl);
  convert_w1<<<(N1_ * K1_) / 256, 256, 0, stream>>>(W1, w1h, w1l);
  convert_w2<<<(N2_ * K2_) / 256, 256, 0, stream>>>(W2, w2h);
  prep_bias <<<4, 256, 0, stream>>>(t, W1, b1, W2, b2, bias1, bias2);
  compute_c <<<256, 256, 0, stream>>>(W1, W2, cvec);
  gemm1_kernel<<<dim3(N1_ / 128, B_ / 128), 256, 0, stream>>>(zh, zl, w1h, w1l, bias1, cvec, hWs, dlogp);
  gemm2_kernel<<<dim3(N2_ / 128, B_ / 128), 256, 0, stream>>>(hWs, w2h, bias2, out);
}